// Round 1
// baseline (785.377 us; speedup 1.0000x reference)
//
#include <hip/hip_runtime.h>
#include <stdint.h>

#define N_ROWS 131072
#define DIM    1024
#define KC     256
#define BM     128
#define BK     64
#define NT     512
#define EPS    1e-8f

typedef unsigned short u16;
typedef short short8 __attribute__((ext_vector_type(8)));
typedef float f32x4  __attribute__((ext_vector_type(4)));

__device__ __forceinline__ u16 f2bf(float f) {
    uint32_t u = __float_as_uint(f);
    u += 0x7FFFu + ((u >> 16) & 1u);   // RNE; inputs are finite
    return (u16)(u >> 16);
}

// ---------------- prep: normalize centroids -> bf16 in ws ----------------
__global__ __launch_bounds__(256) void prep_centroids(const float* __restrict__ cent,
                                                      u16* __restrict__ cnw) {
    const int k = blockIdx.x;       // centroid index 0..255
    const int t = threadIdx.x;      // 256 threads, 4 floats each
    const float4 v = *(const float4*)(cent + (size_t)k * DIM + t * 4);
    float ss = v.x * v.x + v.y * v.y + v.z * v.z + v.w * v.w;
#pragma unroll
    for (int m = 1; m < 64; m <<= 1) ss += __shfl_xor(ss, m);
    __shared__ float wss[4];
    const int wid = t >> 6, lane = t & 63;
    if (lane == 0) wss[wid] = ss;
    __syncthreads();
    const float tot = wss[0] + wss[1] + wss[2] + wss[3];
    const float r = 1.0f / fmaxf(sqrtf(tot), EPS);
    ushort4 o;
    o.x = f2bf(v.x * r); o.y = f2bf(v.y * r);
    o.z = f2bf(v.z * r); o.w = f2bf(v.w * r);
    *(ushort4*)(cnw + (size_t)k * DIM + t * 4) = o;
}

// ---------------- main: fused GEMM + row-norm + softmax ----------------
__global__ __launch_bounds__(NT, 2) void cluster_main(const float* __restrict__ batch,
                                                      const u16* __restrict__ cnw,
                                                      float* __restrict__ out) {
    __shared__ u16 Ab[BM * BK];                    // 16 KiB, XOR-swizzled bf16
    __shared__ u16 Bb[KC * BK];                    // 32 KiB, XOR-swizzled bf16
    __shared__ float s_ss[BM];                     // row sum-of-squares
    __shared__ __align__(16) float s_part[BM][4];  // per-colwave exp partial sums

    const int t    = threadIdx.x;
    const int lane = t & 63;
    const int w    = t >> 6;      // wave 0..7
    const int wm   = w >> 2;      // 0..1  (64-row slab)
    const int wn   = w & 3;       // 0..3  (64-col slab)
    const int l15  = lane & 15;
    const int lhi  = lane >> 4;   // 0..3
    const size_t row0 = (size_t)blockIdx.x * BM;

    // A-staging map: thread covers rows a_row+32*i, 16 consecutive floats each? no:
    // idx = t + i*512 -> row = idx>>4 (a_row+32i), float4 slot = idx&15
    const int a_row = t >> 4;
    const int a_c4  = t & 15;
    // B-staging map: row = t>>1, half = t&1 (32 bf16 each)
    const int b_row  = t >> 1;
    const int b_half = t & 1;

    f32x4 acc[4][4];
#pragma unroll
    for (int i = 0; i < 4; ++i)
#pragma unroll
        for (int j = 0; j < 4; ++j) acc[i][j] = (f32x4)0.0f;

    float ss[4] = {0.f, 0.f, 0.f, 0.f};

    for (int kt = 0; kt < DIM / BK; ++kt) {
        const int d0 = kt * BK;
        // ---- stage A (fp32 -> bf16, fused sumsq) ----
#pragma unroll
        for (int i = 0; i < 4; ++i) {
            const int r = a_row + 32 * i;
            const float4 v = *(const float4*)(batch + (row0 + r) * (size_t)DIM + d0 + a_c4 * 4);
            ss[i] += v.x * v.x + v.y * v.y + v.z * v.z + v.w * v.w;
            uint2 p;
            p.x = (uint32_t)f2bf(v.x) | ((uint32_t)f2bf(v.y) << 16);
            p.y = (uint32_t)f2bf(v.z) | ((uint32_t)f2bf(v.w) << 16);
            const int byte = (r * (BK * 2) + a_c4 * 8) ^ ((r & 7) << 4);
            *(uint2*)((char*)Ab + byte) = p;
        }
        // ---- stage B (pre-normalized bf16 from ws) ----
#pragma unroll
        for (int j = 0; j < 4; ++j) {
            const uint4 v = *(const uint4*)(cnw + (size_t)b_row * DIM + d0 + b_half * 32 + j * 8);
            const int byte = (b_row * (BK * 2) + b_half * 64 + j * 16) ^ ((b_row & 7) << 4);
            *(uint4*)((char*)Bb + byte) = v;
        }
        __syncthreads();
        // ---- MFMA over this K-chunk ----
#pragma unroll
        for (int ks = 0; ks < 2; ++ks) {
            short8 af[4], bfr[4];
#pragma unroll
            for (int mi = 0; mi < 4; ++mi) {
                const int r = wm * 64 + mi * 16 + l15;
                const int byte = (r * (BK * 2) + (ks * 32 + lhi * 8) * 2) ^ ((r & 7) << 4);
                af[mi] = *(const short8*)((const char*)Ab + byte);
            }
#pragma unroll
            for (int ni = 0; ni < 4; ++ni) {
                const int r = wn * 64 + ni * 16 + l15;
                const int byte = (r * (BK * 2) + (ks * 32 + lhi * 8) * 2) ^ ((r & 7) << 4);
                bfr[ni] = *(const short8*)((const char*)Bb + byte);
            }
#pragma unroll
            for (int mi = 0; mi < 4; ++mi)
#pragma unroll
                for (int ni = 0; ni < 4; ++ni)
                    acc[mi][ni] = __builtin_amdgcn_mfma_f32_16x16x32_bf16(af[mi], bfr[ni],
                                                                          acc[mi][ni], 0, 0, 0);
        }
        __syncthreads();
    }

    // ---- finalize row norms ----
#pragma unroll
    for (int i = 0; i < 4; ++i) {
        float v = ss[i];
#pragma unroll
        for (int m = 1; m < 16; m <<= 1) v += __shfl_xor(v, m);
        if (a_c4 == 0) s_ss[a_row + 32 * i] = v;
    }
    __syncthreads();

    // ---- epilogue: sim = acc/||x||, softmax over 256 cols ----
    float rnorm[4][4];
#pragma unroll
    for (int mi = 0; mi < 4; ++mi)
#pragma unroll
        for (int q = 0; q < 4; ++q) {
            const int r = wm * 64 + mi * 16 + lhi * 4 + q;
            rnorm[mi][q] = 1.0f / fmaxf(sqrtf(s_ss[r]), EPS);
        }

    float psum[4][4];
#pragma unroll
    for (int mi = 0; mi < 4; ++mi)
#pragma unroll
        for (int q = 0; q < 4; ++q) {
            float s = 0.f;
#pragma unroll
            for (int ni = 0; ni < 4; ++ni) {
                const float e = __expf(acc[mi][ni][q] * rnorm[mi][q]);
                acc[mi][ni][q] = e;   // reuse acc to hold exp values
                s += e;
            }
#pragma unroll
            for (int m = 1; m < 16; m <<= 1) s += __shfl_xor(s, m);
            psum[mi][q] = s;          // this wave's 64-col partial (all 16 lanes hold it)
        }
    if (l15 == 0) {
#pragma unroll
        for (int mi = 0; mi < 4; ++mi)
#pragma unroll
            for (int q = 0; q < 4; ++q)
                s_part[wm * 64 + mi * 16 + lhi * 4 + q][wn] = psum[mi][q];
    }
    __syncthreads();

#pragma unroll
    for (int mi = 0; mi < 4; ++mi)
#pragma unroll
        for (int q = 0; q < 4; ++q) {
            const int r = wm * 64 + mi * 16 + lhi * 4 + q;
            const float4 p = *(const float4*)&s_part[r][0];
            const float rtot = 1.0f / (p.x + p.y + p.z + p.w);
            const size_t ob = (row0 + r) * (size_t)KC + wn * 64 + l15;
#pragma unroll
            for (int ni = 0; ni < 4; ++ni)
                out[ob + ni * 16] = acc[mi][ni][q] * rtot;
        }
}

extern "C" void kernel_launch(void* const* d_in, const int* in_sizes, int n_in,
                              void* d_out, int out_size, void* d_ws, size_t ws_size,
                              hipStream_t stream) {
    const float* batch = (const float*)d_in[0];
    const float* cent  = (const float*)d_in[1];
    float* out = (float*)d_out;
    u16* cnw = (u16*)d_ws;   // 256*1024 bf16 = 512 KiB

    prep_centroids<<<KC, 256, 0, stream>>>(cent, cnw);
    cluster_main<<<N_ROWS / BM, NT, 0, stream>>>(batch, cnw, out);
}

// Round 2
// 773.448 us; speedup vs baseline: 1.0154x; 1.0154x over previous
//
#include <hip/hip_runtime.h>
#include <stdint.h>

#define N_ROWS 131072
#define DIM    1024
#define KC     256
#define BM     128
#define BK     64
#define NT     1024
#define NIT    (DIM / BK)   // 16
#define EPS    1e-8f

typedef unsigned short u16;
typedef short short8 __attribute__((ext_vector_type(8)));
typedef float f32x4  __attribute__((ext_vector_type(4)));

__device__ __forceinline__ u16 f2bf(float f) {
    uint32_t u = __float_as_uint(f);
    u += 0x7FFFu + ((u >> 16) & 1u);   // RNE; inputs finite
    return (u16)(u >> 16);
}

__device__ __forceinline__ void gload_lds16(const void* g, void* l) {
    __builtin_amdgcn_global_load_lds(
        (const __attribute__((address_space(1))) void*)g,
        (__attribute__((address_space(3))) void*)l, 16, 0, 0);
}

// ---------------- prep: normalize centroids -> bf16 in ws ----------------
__global__ __launch_bounds__(256) void prep_centroids(const float* __restrict__ cent,
                                                      u16* __restrict__ cnw) {
    const int k = blockIdx.x;
    const int t = threadIdx.x;
    const float4 v = *(const float4*)(cent + (size_t)k * DIM + t * 4);
    float ss = v.x * v.x + v.y * v.y + v.z * v.z + v.w * v.w;
#pragma unroll
    for (int m = 1; m < 64; m <<= 1) ss += __shfl_xor(ss, m);
    __shared__ float wss[4];
    const int wid = t >> 6, lane = t & 63;
    if (lane == 0) wss[wid] = ss;
    __syncthreads();
    const float tot = wss[0] + wss[1] + wss[2] + wss[3];
    const float r = 1.0f / fmaxf(sqrtf(tot), EPS);
    ushort4 o;
    o.x = f2bf(v.x * r); o.y = f2bf(v.y * r);
    o.z = f2bf(v.z * r); o.w = f2bf(v.w * r);
    *(ushort4*)(cnw + (size_t)k * DIM + t * 4) = o;
}

// ---------------- main: pipelined GEMM + row-norm + softmax ----------------
// 1024 thr = 16 waves (4x4 wave grid); wave tile 32 rows x 64 cols; acc[2][4].
// B: global_load_lds double-buffered (pre-swizzled source, swizzled read).
// A: reg-prefetch (k+1) under MFMA(k), convert+sumsq+swizzled ds_write.
__global__ __launch_bounds__(NT) void cluster_main(const float* __restrict__ batch,
                                                   const u16* __restrict__ cnw,
                                                   float* __restrict__ out) {
    __shared__ u16 Ab[BM * BK];          // 16 KiB, single-buffered, XOR-swizzled
    __shared__ u16 Bb[2][KC * BK];       // 2 x 32 KiB, linear-dest for gload_lds
    __shared__ float s_ss[BM];
    __shared__ __align__(16) float s_part[BM][4];

    const int t    = threadIdx.x;
    const int lane = t & 63;
    const int w    = t >> 6;      // 0..15
    const int wm   = w >> 2;      // 0..3 (32-row slab)
    const int wn   = w & 3;       // 0..3 (64-col slab)
    const int l15  = lane & 15;
    const int lhi  = lane >> 4;
    const size_t row0 = (size_t)blockIdx.x * BM;

    // ---- A staging map: thread covers rows (t>>4) and (t>>4)+64, float4 slot t&15
    const int a_row = t >> 4;     // 0..63
    const int a_c4  = t & 15;
    const float* a_ptr0 = batch + (row0 + a_row) * (size_t)DIM + a_c4 * 4;
    const float* a_ptr1 = a_ptr0 + (size_t)64 * DIM;
    const int awb0 = (a_row * 128 + a_c4 * 8) ^ ((a_row & 7) << 4);          // byte
    const int awb1 = ((a_row + 64) * 128 + a_c4 * 8) ^ ((a_row & 7) << 4);   // same XOR

    // ---- B gload map: issue j: LDS byte p = j*16384 + t*16 (linear dest)
    // row = j*128 + (t>>3); src col-bytes = ((t&7)*16) ^ ((row&7)<<4)
    const int b_r  = t >> 3;                                  // 0..127
    const int b_cb = ((t & 7) * 16) ^ ((b_r & 7) << 4);       // bytes, same for j=0,1
    const u16* bsrc0 = cnw + (size_t)b_r * DIM + (b_cb >> 1);
    const u16* bsrc1 = cnw + (size_t)(b_r + 128) * DIM + (b_cb >> 1);
    const int bdst0 = w * 512;            // u16 idx, wave-uniform (lane*16B auto)
    const int bdst1 = 8192 + w * 512;

    f32x4 acc[2][4];
#pragma unroll
    for (int i = 0; i < 2; ++i)
#pragma unroll
        for (int j = 0; j < 4; ++j) acc[i][j] = (f32x4)0.0f;
    float ss0 = 0.f, ss1 = 0.f;

    // ---- prologue: stage chunk 0 ----
    {
        gload_lds16(bsrc0, &Bb[0][bdst0]);
        gload_lds16(bsrc1, &Bb[0][bdst1]);
        const float4 v0 = *(const float4*)a_ptr0;
        const float4 v1 = *(const float4*)a_ptr1;
        ss0 += v0.x * v0.x + v0.y * v0.y + v0.z * v0.z + v0.w * v0.w;
        ss1 += v1.x * v1.x + v1.y * v1.y + v1.z * v1.z + v1.w * v1.w;
        uint2 p0, p1;
        p0.x = (uint32_t)f2bf(v0.x) | ((uint32_t)f2bf(v0.y) << 16);
        p0.y = (uint32_t)f2bf(v0.z) | ((uint32_t)f2bf(v0.w) << 16);
        p1.x = (uint32_t)f2bf(v1.x) | ((uint32_t)f2bf(v1.y) << 16);
        p1.y = (uint32_t)f2bf(v1.z) | ((uint32_t)f2bf(v1.w) << 16);
        *(uint2*)((char*)Ab + awb0) = p0;
        *(uint2*)((char*)Ab + awb1) = p1;
        __syncthreads();   // drains gload_lds(B0) too
    }

    for (int kt = 0; kt < NIT; ++kt) {
        const int cur = kt & 1;
        // ---- prefetch k+1: B -> LDS[cur^1] (async DMA), A -> regs ----
        float4 va0, va1;
        if (kt < NIT - 1) {
            const int d0n = (kt + 1) * BK;
            gload_lds16(bsrc0 + d0n, &Bb[cur ^ 1][bdst0]);
            gload_lds16(bsrc1 + d0n, &Bb[cur ^ 1][bdst1]);
            va0 = *(const float4*)(a_ptr0 + d0n);
            va1 = *(const float4*)(a_ptr1 + d0n);
        }
        __builtin_amdgcn_sched_barrier(0);   // pin prefetch issue above MFMA phase

        // ---- MFMA phase on Ab, Bb[cur] ----
#pragma unroll
        for (int ks = 0; ks < 2; ++ks) {
            short8 af[2], bfr[4];
#pragma unroll
            for (int mi = 0; mi < 2; ++mi) {
                const int r = wm * 32 + mi * 16 + l15;
                const int byte = (r * 128 + ks * 64 + lhi * 16) ^ ((r & 7) << 4);
                af[mi] = *(const short8*)((const char*)Ab + byte);
            }
#pragma unroll
            for (int ni = 0; ni < 4; ++ni) {
                const int r = wn * 64 + ni * 16 + l15;
                const int byte = (r * 128 + ks * 64 + lhi * 16) ^ ((r & 7) << 4);
                bfr[ni] = *(const short8*)((const char*)&Bb[cur][0] + byte);
            }
#pragma unroll
            for (int mi = 0; mi < 2; ++mi)
#pragma unroll
                for (int ni = 0; ni < 4; ++ni)
                    acc[mi][ni] = __builtin_amdgcn_mfma_f32_16x16x32_bf16(af[mi], bfr[ni],
                                                                          acc[mi][ni], 0, 0, 0);
        }
        __syncthreads();   // Ab/Bb[cur] reads done; drains in-flight prefetches

        // ---- convert + sumsq + write A(k+1) into Ab ----
        if (kt < NIT - 1) {
            ss0 += va0.x * va0.x + va0.y * va0.y + va0.z * va0.z + va0.w * va0.w;
            ss1 += va1.x * va1.x + va1.y * va1.y + va1.z * va1.z + va1.w * va1.w;
            uint2 p0, p1;
            p0.x = (uint32_t)f2bf(va0.x) | ((uint32_t)f2bf(va0.y) << 16);
            p0.y = (uint32_t)f2bf(va0.z) | ((uint32_t)f2bf(va0.w) << 16);
            p1.x = (uint32_t)f2bf(va1.x) | ((uint32_t)f2bf(va1.y) << 16);
            p1.y = (uint32_t)f2bf(va1.z) | ((uint32_t)f2bf(va1.w) << 16);
            *(uint2*)((char*)Ab + awb0) = p0;
            *(uint2*)((char*)Ab + awb1) = p1;
        }
        __syncthreads();
    }

    // ---- finalize row norms ----
    {
        float v0 = ss0, v1 = ss1;
#pragma unroll
        for (int m = 1; m < 16; m <<= 1) { v0 += __shfl_xor(v0, m); v1 += __shfl_xor(v1, m); }
        if (a_c4 == 0) { s_ss[a_row] = v0; s_ss[a_row + 64] = v1; }
    }
    __syncthreads();

    // ---- epilogue: sim = acc/||x||, softmax over 256 cols ----
    float psum[2][4];
#pragma unroll
    for (int mi = 0; mi < 2; ++mi)
#pragma unroll
        for (int q = 0; q < 4; ++q) {
            const int r = wm * 32 + mi * 16 + lhi * 4 + q;
            const float rn = 1.0f / fmaxf(sqrtf(s_ss[r]), EPS);
            float s = 0.f;
#pragma unroll
            for (int ni = 0; ni < 4; ++ni) {
                const float e = __expf(acc[mi][ni][q] * rn);
                acc[mi][ni][q] = e;
                s += e;
            }
#pragma unroll
            for (int m = 1; m < 16; m <<= 1) s += __shfl_xor(s, m);
            psum[mi][q] = s;
        }
    if (l15 == 0) {
#pragma unroll
        for (int mi = 0; mi < 2; ++mi)
#pragma unroll
            for (int q = 0; q < 4; ++q)
                s_part[wm * 32 + mi * 16 + lhi * 4 + q][wn] = psum[mi][q];
    }
    __syncthreads();

#pragma unroll
    for (int mi = 0; mi < 2; ++mi)
#pragma unroll
        for (int q = 0; q < 4; ++q) {
            const int r = wm * 32 + mi * 16 + lhi * 4 + q;
            const float4 p = *(const float4*)&s_part[r][0];
            const float rtot = 1.0f / (p.x + p.y + p.z + p.w);
            const size_t ob = (row0 + r) * (size_t)KC + wn * 64 + l15;
#pragma unroll
            for (int ni = 0; ni < 4; ++ni)
                out[ob + ni * 16] = acc[mi][ni][q] * rtot;
        }
}

extern "C" void kernel_launch(void* const* d_in, const int* in_sizes, int n_in,
                              void* d_out, int out_size, void* d_ws, size_t ws_size,
                              hipStream_t stream) {
    const float* batch = (const float*)d_in[0];
    const float* cent  = (const float*)d_in[1];
    float* out = (float*)d_out;
    u16* cnw = (u16*)d_ws;   // 256*1024 bf16 = 512 KiB

    prep_centroids<<<KC, 256, 0, stream>>>(cent, cnw);
    cluster_main<<<N_ROWS / BM, NT, 0, stream>>>(batch, cnw, out);
}